// Round 6
// baseline (201.489 us; speedup 1.0000x reference)
//
#include <hip/hip_runtime.h>
#include <hip/hip_bf16.h>
#include <stdint.h>

#define WW    361    // W*W spatial positions
#define CCH   64     // channels (K)
#define MH    192    // support rows per block (i-half, 12 tiles)
#define NQR   368    // query rows padded to 23 tiles of 16
#define NT    23
#define NTHR  512    // 8 waves
#define WWC   (WW*CCH)

typedef __attribute__((ext_vector_type(8))) short short8;
typedef __attribute__((ext_vector_type(4))) float f32x4;

// R6: back to R0's spill-free primitives; overlap via occupancy, not
// in-thread pipelining (R2/R4/R5: any gather array held across a phase is
// demoted to scratch -> 78-345MB WRITE_SIZE).
//   - LDS = Q only (368 rows bf16 swizzled + inv_q = 48.6 KB) -> 3 blocks/CU.
//   - S gathered per-wave straight into named f32x4s, consumed immediately.
//   - block=(bs,i-half); XCD swizzle keeps both halves of a bs on one XCD
//     so the second Q read is an L2 hit.
// LDS row layout: pitch 64 bf16 (128B), 16B-granule XOR swizzle (g ^ (m&7));
// bank-uniform for b128 writes and b128 fragment reads (proven R1/R2).

// Stage one Q row: 64 strided floats, bf16-pack, swizzled b128 writes,
// returns rsqrt(sumsq). R0-proven spill-free shape.
__device__ __forceinline__ float stage_row(const float* __restrict__ gp,
                                           unsigned short* __restrict__ dst, int sw) {
  float a0 = 0.f, a1 = 0.f;
  #pragma unroll
  for (int c = 0; c < 8; ++c) {
    float v[8];
    #pragma unroll
    for (int j = 0; j < 8; ++j) v[j] = gp[(c * 8 + j) * WW];  // coalesced
    unsigned int u[4];
    #pragma unroll
    for (int jj = 0; jj < 4; ++jj) {
      a0 += v[2*jj] * v[2*jj];
      a1 += v[2*jj+1] * v[2*jj+1];
      __hip_bfloat162 b2 = __float22bfloat162_rn(make_float2(v[2*jj], v[2*jj+1]));
      u[jj] = *(unsigned int*)&b2;
    }
    *(uint4*)&dst[(c ^ sw) * 8] = make_uint4(u[0], u[1], u[2], u[3]);
  }
  return rsqrtf(a0 + a1);
}

__device__ __forceinline__ void zero_row(unsigned short* __restrict__ dst) {
  #pragma unroll
  for (int c = 0; c < 8; ++c)
    *(uint4*)&dst[c * 8] = make_uint4(0u, 0u, 0u, 0u);
}

// gather this lane's A-row channels (k = 8q..8q+7 and 32+8q..32+8q+7)
__device__ __forceinline__ void gatherA(const float* __restrict__ srow, bool valid,
                                        int quad, f32x4& w0, f32x4& w1,
                                        f32x4& w2, f32x4& w3) {
  if (valid) {
    #pragma unroll
    for (int j = 0; j < 4; ++j) w0[j] = srow[(8 * quad + j) * WW];
    #pragma unroll
    for (int j = 0; j < 4; ++j) w1[j] = srow[(8 * quad + 4 + j) * WW];
    #pragma unroll
    for (int j = 0; j < 4; ++j) w2[j] = srow[(32 + 8 * quad + j) * WW];
    #pragma unroll
    for (int j = 0; j < 4; ++j) w3[j] = srow[(32 + 8 * quad + 4 + j) * WW];
  } else {
    w0 = (f32x4){0.f, 0.f, 0.f, 0.f}; w1 = w0; w2 = w0; w3 = w0;
  }
}

// pack gathered floats into A fragments; row sumsq reduced across the 4 quads
__device__ __forceinline__ void buildA(f32x4 w0, f32x4 w1, f32x4 w2, f32x4 w3,
                                       bool valid, short8& af0, short8& af1,
                                       float& invA) {
  unsigned int u[8];
  float ss = 0.f;
  #pragma unroll
  for (int p = 0; p < 2; ++p) {
    __hip_bfloat162 b2 = __float22bfloat162_rn(make_float2(w0[2*p], w0[2*p+1]));
    u[p] = *(unsigned int*)&b2;
    ss += w0[2*p] * w0[2*p] + w0[2*p+1] * w0[2*p+1];
    b2 = __float22bfloat162_rn(make_float2(w1[2*p], w1[2*p+1]));
    u[2 + p] = *(unsigned int*)&b2;
    ss += w1[2*p] * w1[2*p] + w1[2*p+1] * w1[2*p+1];
    b2 = __float22bfloat162_rn(make_float2(w2[2*p], w2[2*p+1]));
    u[4 + p] = *(unsigned int*)&b2;
    ss += w2[2*p] * w2[2*p] + w2[2*p+1] * w2[2*p+1];
    b2 = __float22bfloat162_rn(make_float2(w3[2*p], w3[2*p+1]));
    u[6 + p] = *(unsigned int*)&b2;
    ss += w3[2*p] * w3[2*p] + w3[2*p+1] * w3[2*p+1];
  }
  ss += __shfl_xor(ss, 16);
  ss += __shfl_xor(ss, 32);
  uint4 t0 = make_uint4(u[0], u[1], u[2], u[3]);
  uint4 t1 = make_uint4(u[4], u[5], u[6], u[7]);
  af0 = *(short8*)&t0;
  af1 = *(short8*)&t1;
  invA = valid ? rsqrtf(ss) : 0.f;
}

__device__ __forceinline__ void epilogue(f32x4 mx, float invA, int tileBase,
                                         int quad, int l15,
                                         float* __restrict__ outb) {
  #pragma unroll
  for (int d = 1; d < 16; d <<= 1) {
    #pragma unroll
    for (int r = 0; r < 4; ++r) mx[r] = fmaxf(mx[r], __shfl_xor(mx[r], d));
  }
  const float iv0 = __shfl(invA, 4 * quad + 0);
  const float iv1 = __shfl(invA, 4 * quad + 1);
  const float iv2 = __shfl(invA, 4 * quad + 2);
  const float iv3 = __shfl(invA, 4 * quad + 3);
  if (l15 == 0) {
    const int mb = tileBase + 4 * quad;
    if (mb + 0 < WW) outb[mb + 0] = mx[0] * iv0;
    if (mb + 1 < WW) outb[mb + 1] = mx[1] * iv1;
    if (mb + 2 < WW) outb[mb + 2] = mx[2] * iv2;
    if (mb + 3 < WW) outb[mb + 3] = mx[3] * iv3;
  }
}

__global__ __launch_bounds__(NTHR, 6) void cossim_max_kernel(
    const float* __restrict__ support, const float* __restrict__ query,
    float* __restrict__ out)
{
  __shared__ __align__(16) unsigned short Q_sh[NQR * CCH];  // 47104 B
  __shared__ float inv_q[NQR];                              //  1472 B -> 48576

  const int tid  = threadIdx.x;
  // XCD-pair swizzle: 1200 = 8*150; both halves of a bs land on one XCD
  const int b    = ((int)blockIdx.x & 7) * 150 + ((int)blockIdx.x >> 3);
  const int bs   = b >> 1;
  const int mBase = (b & 1) * MH;

  const int lane = tid & 63;
  const int wv   = tid >> 6;     // 0..7
  const int l15  = lane & 15;
  const int quad = lane >> 4;

  const float* sg = support + (size_t)bs * WWC;
  const float* qg = query   + (size_t)bs * WWC;

  // i-tile assignment: wave w owns tile w; waves 4..7 also own tiles 8..11
  // (waves 0..5 carry the Q staging, so give the extra tiles to 4..7)
  const int t0   = wv;
  const int t1   = wv + 4;             // meaningful only for wv >= 4
  const bool two = (wv >= 4);
  const int iG0  = mBase + 16 * t0 + l15;
  const int iG1  = mBase + 16 * t1 + l15;

  // ---- issue tile-0 S gather, then stage Q (gather latency hides under it) ----
  f32x4 w0, w1, w2, w3;
  gatherA(sg + iG0, iG0 < WW, quad, w0, w1, w2, w3);

  if (tid < NQR) {
    if (tid < WW) inv_q[tid] = stage_row(qg + tid, &Q_sh[tid * CCH], tid & 7);
    else { zero_row(&Q_sh[tid * CCH]); inv_q[tid] = 0.f; }
  }

  short8 af00, af01; float invA0;
  buildA(w0, w1, w2, w3, iG0 < WW, af00, af01, invA0);

  short8 af10 = af00, af11 = af01; float invA1 = 0.f;
  if (two) {
    gatherA(sg + iG1, iG1 < WW, quad, w0, w1, w2, w3);
    buildA(w0, w1, w2, w3, iG1 < WW, af10, af11, invA1);
  }

  __syncthreads();

  // ---- compute: 23 q-tiles from swizzled LDS ----
  const int boff0 = l15 * CCH + ((quad       ^ (l15 & 7)) * 8);
  const int boff1 = l15 * CCH + (((4 + quad) ^ (l15 & 7)) * 8);
  const float lastbias = (l15 < 9) ? 0.f : -1e30f;  // tile 22: n = 352+l15
  const bool t1live = two && (mBase + 16 * t1) < WW;

  f32x4 mx0 = {-3e38f, -3e38f, -3e38f, -3e38f};
  f32x4 mx1 = mx0;

  for (int t = 0; t < NT; ++t) {
    const int nb = t * 16 * CCH;
    short8 b0 = *(const short8*)&Q_sh[nb + boff0];
    short8 b1 = *(const short8*)&Q_sh[nb + boff1];
    const float qs = inv_q[t * 16 + l15];
    const float bb = (t == NT - 1) ? lastbias : 0.f;
    f32x4 acc = {0.f, 0.f, 0.f, 0.f};
    __builtin_amdgcn_s_setprio(1);
    acc = __builtin_amdgcn_mfma_f32_16x16x32_bf16(af00, b0, acc, 0, 0, 0);
    acc = __builtin_amdgcn_mfma_f32_16x16x32_bf16(af01, b1, acc, 0, 0, 0);
    __builtin_amdgcn_s_setprio(0);
    #pragma unroll
    for (int r = 0; r < 4; ++r) mx0[r] = fmaxf(mx0[r], acc[r] * qs + bb);
    if (t1live) {
      f32x4 acc2 = {0.f, 0.f, 0.f, 0.f};
      __builtin_amdgcn_s_setprio(1);
      acc2 = __builtin_amdgcn_mfma_f32_16x16x32_bf16(af10, b0, acc2, 0, 0, 0);
      acc2 = __builtin_amdgcn_mfma_f32_16x16x32_bf16(af11, b1, acc2, 0, 0, 0);
      __builtin_amdgcn_s_setprio(0);
      #pragma unroll
      for (int r = 0; r < 4; ++r) mx1[r] = fmaxf(mx1[r], acc2[r] * qs + bb);
    }
  }

  float* outb = out + (size_t)bs * WW;
  epilogue(mx0, invA0, mBase + 16 * t0, quad, l15, outb);
  if (t1live) epilogue(mx1, invA1, mBase + 16 * t1, quad, l15, outb);
}

extern "C" void kernel_launch(void* const* d_in, const int* in_sizes, int n_in,
                              void* d_out, int out_size, void* d_ws, size_t ws_size,
                              hipStream_t stream) {
  const float* support = (const float*)d_in[0];
  const float* query   = (const float*)d_in[1];
  float* out = (float*)d_out;
  dim3 grid(1200), block(NTHR);
  hipLaunchKernelGGL(cossim_max_kernel, grid, block, 0, stream,
                     support, query, out);
}

// Round 7
// 151.454 us; speedup vs baseline: 1.3304x; 1.3304x over previous
//
#include <hip/hip_runtime.h>
#include <hip/hip_bf16.h>
#include <stdint.h>

#define WW    361    // W*W spatial positions
#define CCH   64     // channels (K)
#define NTHR  256    // 4 waves; __launch_bounds__(256,4) -> 128 VGPR cap
#define WWC   (WW*CCH)
#define NOUT  (600*WW)

typedef __attribute__((ext_vector_type(8))) short short8;
typedef __attribute__((ext_vector_type(4))) float f32x4;

// R7: block = (bs, i-half, q-half), 256 thr, 4 blocks/CU. Latency hidden by
// cross-block TLP (4 independent staging/compute streams per CU), NOT by
// in-thread pipelining (R2/R4/R5/R6: every cross-phase register array under
// a *,6 launch-bound (85-VGPR cap) spilled; here cap=128 and nothing is
// held across a phase). 3 i-tiles/wave share each B-fragment (3x MFMA per
// ds_read). Cross-q-half max via atomicMax on order-preserving uint
// encoding; decode kernel restores f32.
// LDS row layout: pitch 64 bf16 (128B), 16B-granule XOR swizzle (g ^ (m&7));
// bank-uniform for b128 writes and b128 fragment reads (proven R1/R2).

__device__ __forceinline__ unsigned int encf(float f) {
  unsigned int b = __float_as_uint(f);
  return (b & 0x80000000u) ? ~b : (b | 0x80000000u);  // monotone f32 -> u32
}

// Stage one Q row: 64 strided floats, bf16-pack, swizzled b128 writes,
// returns rsqrt(sumsq). R0-proven spill-free shape (VGPR 40).
__device__ __forceinline__ float stage_row(const float* __restrict__ gp,
                                           unsigned short* __restrict__ dst, int sw) {
  float a0 = 0.f, a1 = 0.f;
  #pragma unroll
  for (int c = 0; c < 8; ++c) {
    float v[8];
    #pragma unroll
    for (int j = 0; j < 8; ++j) v[j] = gp[(c * 8 + j) * WW];  // coalesced
    unsigned int u[4];
    #pragma unroll
    for (int jj = 0; jj < 4; ++jj) {
      a0 += v[2*jj] * v[2*jj];
      a1 += v[2*jj+1] * v[2*jj+1];
      __hip_bfloat162 b2 = __float22bfloat162_rn(make_float2(v[2*jj], v[2*jj+1]));
      u[jj] = *(unsigned int*)&b2;
    }
    *(uint4*)&dst[(c ^ sw) * 8] = make_uint4(u[0], u[1], u[2], u[3]);
  }
  return rsqrtf(a0 + a1);
}

__device__ __forceinline__ void zero_row(unsigned short* __restrict__ dst) {
  #pragma unroll
  for (int c = 0; c < 8; ++c)
    *(uint4*)&dst[c * 8] = make_uint4(0u, 0u, 0u, 0u);
}

// gather + build one A-tile fragment pair; loads consumed immediately
__device__ __forceinline__ void makeA(const float* __restrict__ srow, bool valid,
                                      int quad, short8& af0, short8& af1,
                                      float& invA) {
  float w[16];
  if (valid) {
    #pragma unroll
    for (int j = 0; j < 8; ++j) w[j]     = srow[(8 * quad + j) * WW];
    #pragma unroll
    for (int j = 0; j < 8; ++j) w[8 + j] = srow[(32 + 8 * quad + j) * WW];
  } else {
    #pragma unroll
    for (int j = 0; j < 16; ++j) w[j] = 0.f;
  }
  unsigned int u[8];
  float ss = 0.f;
  #pragma unroll
  for (int jj = 0; jj < 8; ++jj) {
    float x = w[2 * jj], y = w[2 * jj + 1];
    ss += x * x + y * y;
    __hip_bfloat162 b2 = __float22bfloat162_rn(make_float2(x, y));
    u[jj] = *(unsigned int*)&b2;
  }
  ss += __shfl_xor(ss, 16);
  ss += __shfl_xor(ss, 32);
  uint4 t0 = make_uint4(u[0], u[1], u[2], u[3]);
  uint4 t1 = make_uint4(u[4], u[5], u[6], u[7]);
  af0 = *(short8*)&t0;
  af1 = *(short8*)&t1;
  invA = valid ? rsqrtf(ss) : 0.f;
}

__device__ __forceinline__ void epilogueAtomic(f32x4 mx, float invA, int tileBase,
                                               int quad, int l15,
                                               unsigned int* __restrict__ outb) {
  #pragma unroll
  for (int d = 1; d < 16; d <<= 1) {
    #pragma unroll
    for (int r = 0; r < 4; ++r) mx[r] = fmaxf(mx[r], __shfl_xor(mx[r], d));
  }
  const float iv0 = __shfl(invA, 4 * quad + 0);
  const float iv1 = __shfl(invA, 4 * quad + 1);
  const float iv2 = __shfl(invA, 4 * quad + 2);
  const float iv3 = __shfl(invA, 4 * quad + 3);
  if (l15 == 0) {
    const int mb = tileBase + 4 * quad;
    if (mb + 0 < WW) atomicMax(&outb[mb + 0], encf(mx[0] * iv0));
    if (mb + 1 < WW) atomicMax(&outb[mb + 1], encf(mx[1] * iv1));
    if (mb + 2 < WW) atomicMax(&outb[mb + 2], encf(mx[2] * iv2));
    if (mb + 3 < WW) atomicMax(&outb[mb + 3], encf(mx[3] * iv3));
  }
}

__global__ __launch_bounds__(NTHR, 4) void cossim_max_kernel(
    const float* __restrict__ support, const float* __restrict__ query,
    unsigned int* __restrict__ outenc)
{
  __shared__ __align__(16) unsigned short Q_sh[192 * CCH];  // 24576 B
  __shared__ float inv_q[192];                              //   768 B

  const int tid  = threadIdx.x;
  const int lane = tid & 63;
  const int wv   = tid >> 6;     // 0..3
  const int l15  = lane & 15;
  const int quad = lane >> 4;

  // XCD-chunk swizzle: 2400 = 8*300; the 4 sub-blocks of one bs run
  // adjacently on one XCD -> duplicate S/Q reads hit that XCD's L2.
  const int b  = ((int)blockIdx.x & 7) * 300 + ((int)blockIdx.x >> 3);
  const int bs = b >> 2;
  const int qh = b & 1;          // q-half
  const int ih = (b >> 1) & 1;   // i-half
  const int qBase = qh * 192;
  const int mBase = ih * 192;

  const float* sg = support + (size_t)bs * WWC;
  const float* qg = query   + (size_t)bs * WWC;

  // ---- Q staging: threads 0..191, one row each (R0 primitive) ----
  const int nreal = qh ? (WW - 192) : 192;   // 169 real rows in half 1
  if (tid < 192) {
    if (tid < nreal) {
      inv_q[tid] = stage_row(qg + qBase + tid, &Q_sh[tid * CCH], tid & 7);
    } else if (tid < 176) {      // rows 169..175 read by tile 10 -> zero
      zero_row(&Q_sh[tid * CCH]);
      inv_q[tid] = 0.f;
    }                            // rows 176..191 never read (NTB=11)
  }

  // ---- A fragments: 3 i-tiles per wave, gather+build immediately ----
  short8 af[3][2]; float invA[3];
  #pragma unroll
  for (int tt = 0; tt < 3; ++tt) {
    const int iG = mBase + 16 * (3 * wv + tt) + l15;
    makeA(sg + iG, iG < WW, quad, af[tt][0], af[tt][1], invA[tt]);
  }

  __syncthreads();

  // ---- compute: NTB q-tiles from swizzled LDS; 3 MFMA pairs per B-frag ----
  const int boff0 = l15 * CCH + ((quad       ^ (l15 & 7)) * 8);
  const int boff1 = l15 * CCH + (((4 + quad) ^ (l15 & 7)) * 8);
  const int NTB = qh ? 11 : 12;
  // half1 tile 10 covers global q-rows 352+l15 -> pad for l15 >= 9
  const float lastbias = (qh && l15 >= 9) ? -1e30f : 0.f;

  f32x4 mx0 = {-3e38f, -3e38f, -3e38f, -3e38f};
  f32x4 mx1 = mx0, mx2 = mx0;

  for (int t = 0; t < NTB; ++t) {
    const int nb = t * 16 * CCH;
    short8 b0 = *(const short8*)&Q_sh[nb + boff0];
    short8 b1 = *(const short8*)&Q_sh[nb + boff1];
    const float qs = inv_q[t * 16 + l15];
    const float bb = (t == NTB - 1) ? lastbias : 0.f;
    f32x4 a0 = {0.f, 0.f, 0.f, 0.f}, a1 = a0, a2 = a0;
    __builtin_amdgcn_s_setprio(1);
    a0 = __builtin_amdgcn_mfma_f32_16x16x32_bf16(af[0][0], b0, a0, 0, 0, 0);
    a0 = __builtin_amdgcn_mfma_f32_16x16x32_bf16(af[0][1], b1, a0, 0, 0, 0);
    a1 = __builtin_amdgcn_mfma_f32_16x16x32_bf16(af[1][0], b0, a1, 0, 0, 0);
    a1 = __builtin_amdgcn_mfma_f32_16x16x32_bf16(af[1][1], b1, a1, 0, 0, 0);
    a2 = __builtin_amdgcn_mfma_f32_16x16x32_bf16(af[2][0], b0, a2, 0, 0, 0);
    a2 = __builtin_amdgcn_mfma_f32_16x16x32_bf16(af[2][1], b1, a2, 0, 0, 0);
    __builtin_amdgcn_s_setprio(0);
    #pragma unroll
    for (int r = 0; r < 4; ++r) {
      mx0[r] = fmaxf(mx0[r], a0[r] * qs + bb);
      mx1[r] = fmaxf(mx1[r], a1[r] * qs + bb);
      mx2[r] = fmaxf(mx2[r], a2[r] * qs + bb);
    }
  }

  unsigned int* outb = outenc + (size_t)bs * WW;
  epilogueAtomic(mx0, invA[0], mBase + 16 * (3 * wv + 0), quad, l15, outb);
  epilogueAtomic(mx1, invA[1], mBase + 16 * (3 * wv + 1), quad, l15, outb);
  epilogueAtomic(mx2, invA[2], mBase + 16 * (3 * wv + 2), quad, l15, outb);
}

__global__ void cossim_decode(unsigned int* __restrict__ p) {
  const int i = blockIdx.x * blockDim.x + threadIdx.x;
  if (i < NOUT) {
    const unsigned int u = p[i];
    p[i] = (u & 0x80000000u) ? (u & 0x7fffffffu) : ~u;  // inverse of encf
  }
}

extern "C" void kernel_launch(void* const* d_in, const int* in_sizes, int n_in,
                              void* d_out, int out_size, void* d_ws, size_t ws_size,
                              hipStream_t stream) {
  const float* support = (const float*)d_in[0];
  const float* query   = (const float*)d_in[1];
  unsigned int* outenc = (unsigned int*)d_out;
  hipMemsetAsync(d_out, 0, (size_t)out_size, stream);  // encf identity (all encf>0)
  dim3 grid(2400), block(NTHR);
  hipLaunchKernelGGL(cossim_max_kernel, grid, block, 0, stream,
                     support, query, outenc);
  dim3 dgrid((NOUT + 255) / 256), dblock(256);
  hipLaunchKernelGGL(cossim_decode, dgrid, dblock, 0, stream, outenc);
}